// Round 8
// baseline (255.433 us; speedup 1.0000x reference)
//
#include <hip/hip_runtime.h>
#include <hip/hip_fp16.h>

#define N_NODES 100000
#define N_EDGES 1600000
#define HID 64

#define BSH 8                         // bucket = dst >> 8 (256 nodes per bucket)
#define NBKT ((N_NODES + 255) / 256)  // 391
#define CAP 6144                      // fixed tmp region per bucket (mean 4093, sd 64)
#define TILE 4096                     // edges per bucket chunk (32 KB LDS)
#define NCHUNK ((N_EDGES + TILE - 1) / TILE)  // 391

#define HSC 0.015625f                 // 1/64: fp16 range scaling for h/aout (exact pow2)
#define HSCI 64.0f

typedef _Float16 f16x8 __attribute__((ext_vector_type(8)));
typedef float f32x4 __attribute__((ext_vector_type(4)));

// Fused {edge bucketing ∥ layer-0 PRE-gemm} fat kernel (R6, verbatim).
__global__ void __launch_bounds__(512) fused0_kernel(
    const int* __restrict__ src, const int* __restrict__ dst,
    int* __restrict__ bcur, unsigned int* __restrict__ tmp,
    const float* __restrict__ x, const float* __restrict__ preW,
    const float* __restrict__ preb, const float* __restrict__ relW,
    const float* __restrict__ relb, const float* __restrict__ rootW,
    __half* __restrict__ m, __half* __restrict__ aout) {
    extern __shared__ __align__(16) char smem[];
    int tid = threadIdx.x;
    if (blockIdx.x < NCHUNK) {
        unsigned long long* ed = (unsigned long long*)smem;  // 32 KB
        int* cnt = (int*)(smem + 32768);
        int* cnt2 = (int*)(smem + 34368);
        int* scnx = (int*)(smem + 35968);
        int* gbase = (int*)(smem + 37568);
        int* s = (int*)(smem + 39168);                        // 2 KB -> 41216
        int bstart = blockIdx.x * TILE;
        int tcnt = N_EDGES - bstart;
        if (tcnt > TILE) tcnt = TILE;
        if (tcnt < 0) tcnt = 0;
        for (int b = tid; b < NBKT; b += 512) { cnt[b] = 0; cnt2[b] = 0; }
        __syncthreads();
        for (int i = tid; i < tcnt; i += 512) atomicAdd(&cnt[dst[bstart + i] >> BSH], 1);
        __syncthreads();
        s[tid] = (tid < NBKT) ? cnt[tid] : 0;
        __syncthreads();
        for (int off = 1; off < 512; off <<= 1) {
            int add = (tid >= off) ? s[tid - off] : 0;
            __syncthreads();
            s[tid] += add;
            __syncthreads();
        }
        if (tid < NBKT) {
            scnx[tid] = s[tid] - cnt[tid];
            gbase[tid] = tid * CAP + atomicAdd(&bcur[tid], cnt[tid]);
        }
        __syncthreads();
        for (int i = tid; i < tcnt; i += 512) {
            int e = bstart + i;
            int d = dst[e], sc = src[e];
            int b = d >> BSH;
            int pos = scnx[b] + atomicAdd(&cnt2[b], 1);
            ed[pos] = ((unsigned long long)(unsigned)d << 32) | (unsigned)sc;
        }
        __syncthreads();
        for (int i = tid; i < tcnt; i += 512) {
            unsigned long long v = ed[i];
            int d = (int)(v >> 32);
            unsigned sc = (unsigned)v;
            int b = d >> BSH;
            int idx = gbase[b] + (i - scnx[b]);
            if (idx < (b + 1) * CAP)  // statistically unreachable guard
                tmp[idx] = ((unsigned)(d & 255) << 17) | sc;
        }
    } else {
        __half* hs = (__half*)smem;              // 16 KB
        __half* ws = (__half*)(smem + 16384);    // 16 KB
        float* xs = (float*)(smem + 32768);      // 384 f
        float* pw = (float*)(smem + 34304);      // 192 f
        float* pbs = (float*)(smem + 35072);     // 64 f -> 35328
        int g = blockIdx.x - NCHUNK;
        int i0 = g * 128;
#pragma unroll
        for (int it = 0; it < 2; it++) {
            int t = it * 512 + tid;
            int row = t >> 3, c = t & 7;
            const float* wsrc = (row < 64) ? &relW[row * 64 + c * 8]
                                           : &rootW[(row - 64) * 64 + c * 8];
            float4 w0 = *(const float4*)wsrc;
            float4 w1 = *(const float4*)(wsrc + 4);
            uint4 pk;
            __half2* hp = (__half2*)&pk;
            hp[0] = __floats2half2_rn(w0.x, w0.y);
            hp[1] = __floats2half2_rn(w0.z, w0.w);
            hp[2] = __floats2half2_rn(w1.x, w1.y);
            hp[3] = __floats2half2_rn(w1.z, w1.w);
            *(uint4*)&ws[row * 64 + ((c ^ (row & 7)) << 3)] = pk;
        }
        if (tid < 192) pw[tid] = preW[tid];
        if (tid < 64) pbs[tid] = preb[tid];
        if (tid < 384) {  // 512 threads fully cover xs[0..383]
            int gi = i0 * 3 + tid;
            xs[tid] = (gi < N_NODES * 3) ? x[gi] : 0.f;
        }
        __syncthreads();
#pragma unroll
        for (int it = 0; it < 2; it++) {
            int t = it * 512 + tid;
            int row = t >> 3, c = t & 7;
            float v[8];
#pragma unroll
            for (int u = 0; u < 8; u++) {
                int col = c * 8 + u;
                float sv = pbs[col];
                sv = fmaf(xs[row * 3 + 0], pw[col * 3 + 0], sv);
                sv = fmaf(xs[row * 3 + 1], pw[col * 3 + 1], sv);
                sv = fmaf(xs[row * 3 + 2], pw[col * 3 + 2], sv);
                v[u] = fmaxf(sv, 0.f);
            }
            uint4 pk;
            __half2* hp = (__half2*)&pk;
            hp[0] = __floats2half2_rn(v[0], v[1]);
            hp[1] = __floats2half2_rn(v[2], v[3]);
            hp[2] = __floats2half2_rn(v[4], v[5]);
            hp[3] = __floats2half2_rn(v[6], v[7]);
            *(uint4*)&hs[row * 64 + ((c ^ (row & 7)) << 3)] = pk;
        }
        __syncthreads();
        int lane = tid & 63;
        int w = tid >> 6;             // wave 0..7
        int wm = w >> 1, wn = w & 1;  // 4x2 wave grid
        int r = lane & 15, q = lane >> 4;
        f32x4 acc[2][4];
#pragma unroll
        for (int mt = 0; mt < 2; mt++)
#pragma unroll
            for (int nt = 0; nt < 4; nt++) acc[mt][nt] = (f32x4){0.f, 0.f, 0.f, 0.f};
#pragma unroll
        for (int ks = 0; ks < 2; ks++) {
            f16x8 af[2], bf[4];
#pragma unroll
            for (int mt = 0; mt < 2; mt++) {
                int row = wm * 32 + mt * 16 + r;
                int cc = (ks * 4 + q) ^ (row & 7);
                af[mt] = *(const f16x8*)&hs[row * 64 + (cc << 3)];
            }
#pragma unroll
            for (int nt = 0; nt < 4; nt++) {
                int row = wn * 64 + nt * 16 + r;
                int cc = (ks * 4 + q) ^ (row & 7);
                bf[nt] = *(const f16x8*)&ws[row * 64 + (cc << 3)];
            }
#pragma unroll
            for (int mt = 0; mt < 2; mt++)
#pragma unroll
                for (int nt = 0; nt < 4; nt++)
                    acc[mt][nt] = __builtin_amdgcn_mfma_f32_16x16x32_f16(af[mt], bf[nt],
                                                                         acc[mt][nt], 0, 0, 0);
        }
        if (wn == 0) {
#pragma unroll
            for (int mt = 0; mt < 2; mt++) {
                int nb = i0 + wm * 32 + mt * 16 + q * 4;
#pragma unroll
                for (int reg = 0; reg < 4; reg++) {
                    int node = nb + reg;
                    if (node >= N_NODES) continue;
#pragma unroll
                    for (int nt = 0; nt < 4; nt++)
                        m[(long)node * 64 + nt * 16 + r] = __float2half(acc[mt][nt][reg]);
                }
            }
        } else {
            float rb[4];
#pragma unroll
            for (int nt = 0; nt < 4; nt++) rb[nt] = relb[nt * 16 + r] * HSC;
#pragma unroll
            for (int mt = 0; mt < 2; mt++) {
                int nb = i0 + wm * 32 + mt * 16 + q * 4;
#pragma unroll
                for (int reg = 0; reg < 4; reg++) {
                    int node = nb + reg;
                    if (node >= N_NODES) continue;
#pragma unroll
                    for (int nt = 0; nt < 4; nt++)
                        aout[(long)node * 64 + nt * 16 + r] =
                            __float2half(fmaf(acc[mt][nt][reg], HSC, rb[nt]));
                }
            }
        }
    }
}

// Pass B: per bucket CSR finalize (R1 verbatim).
__global__ void __launch_bounds__(256) passb_kernel(const unsigned int* __restrict__ tmp,
                                                    const int* __restrict__ bcur,
                                                    int* __restrict__ rowp,
                                                    int* __restrict__ ssrc) {
    __shared__ int red[256];
    __shared__ int cnt[256], s[256], cur[256];
    int tid = threadIdx.x;
    int b = blockIdx.x;
    int acc = 0;
    for (int i = tid; i < b; i += 256) {
        int c = bcur[i];
        if (c > CAP) c = CAP;
        acc += c;
    }
    red[tid] = acc;
    __syncthreads();
    for (int off = 128; off >= 1; off >>= 1) {
        if (tid < off) red[tid] += red[tid + off];
        __syncthreads();
    }
    int lo = red[0];
    int ne = bcur[b];
    if (ne > CAP) ne = CAP;
    if (b == NBKT - 1 && tid == 0) rowp[N_NODES] = lo + ne;
    int lo_t = b * CAP;
    cnt[tid] = 0;
    __syncthreads();
    for (int i = tid; i < ne; i += 256) atomicAdd(&cnt[tmp[lo_t + i] >> 17], 1);
    __syncthreads();
    int v = cnt[tid];
    s[tid] = v;
    __syncthreads();
    for (int off = 1; off < 256; off <<= 1) {
        int a = (tid >= off) ? s[tid - off] : 0;
        __syncthreads();
        s[tid] += a;
        __syncthreads();
    }
    int excl = lo + s[tid] - v;
    int node = (b << BSH) + tid;
    if (node < N_NODES) rowp[node] = excl;
    cur[tid] = excl;
    __syncthreads();
    for (int i = tid; i < ne; i += 256) {
        unsigned u = tmp[lo_t + i];
        int pos = atomicAdd(&cur[u >> 17], 1);
        ssrc[pos] = (int)(u & 0x1FFFF);
    }
}

// 8-deep gather body: issue 8 idx loads, then 8 row loads, then accumulate.
// Collapses a mean-degree-16 node (ns=8) into ONE memory round-trip pair
// instead of two 4-deep iterations (R7 counters: all pipes <30% -> latency-
// bound; per-lane queue depth is the lever). VGPR rises to ~80 (16 waves/CU
// cap) — accepted: outstanding-loads/CU still rises ~2.5x.
#define GATHER_BODY(m_ptr)                                                   \
    int ns = nedge >> 1;                                                     \
    int qq = 0;                                                              \
    for (; qq + 8 <= ns; qq += 8) {                                          \
        int b0 = r0 + qq * 2 + g;                                            \
        int j0 = ssrc[b0];                                                   \
        int j1 = ssrc[b0 + 2];                                               \
        int j2 = ssrc[b0 + 4];                                               \
        int j3 = ssrc[b0 + 6];                                               \
        int j4 = ssrc[b0 + 8];                                               \
        int j5 = ssrc[b0 + 10];                                              \
        int j6 = ssrc[b0 + 12];                                              \
        int j7 = ssrc[b0 + 14];                                              \
        uint4 u0 = *(const uint4*)(m_ptr + (long)j0 * 64 + f8);              \
        uint4 u1 = *(const uint4*)(m_ptr + (long)j1 * 64 + f8);              \
        uint4 u2 = *(const uint4*)(m_ptr + (long)j2 * 64 + f8);              \
        uint4 u3 = *(const uint4*)(m_ptr + (long)j3 * 64 + f8);              \
        uint4 u4 = *(const uint4*)(m_ptr + (long)j4 * 64 + f8);              \
        uint4 u5 = *(const uint4*)(m_ptr + (long)j5 * 64 + f8);              \
        uint4 u6 = *(const uint4*)(m_ptr + (long)j6 * 64 + f8);              \
        uint4 u7 = *(const uint4*)(m_ptr + (long)j7 * 64 + f8);              \
        ACC8(u0); ACC8(u1); ACC8(u2); ACC8(u3);                              \
        ACC8(u4); ACC8(u5); ACC8(u6); ACC8(u7);                              \
    }                                                                        \
    if (qq + 4 <= ns) {                                                      \
        int b0 = r0 + qq * 2 + g;                                            \
        int j0 = ssrc[b0];                                                   \
        int j1 = ssrc[b0 + 2];                                               \
        int j2 = ssrc[b0 + 4];                                               \
        int j3 = ssrc[b0 + 6];                                               \
        uint4 u0 = *(const uint4*)(m_ptr + (long)j0 * 64 + f8);              \
        uint4 u1 = *(const uint4*)(m_ptr + (long)j1 * 64 + f8);              \
        uint4 u2 = *(const uint4*)(m_ptr + (long)j2 * 64 + f8);              \
        uint4 u3 = *(const uint4*)(m_ptr + (long)j3 * 64 + f8);              \
        ACC8(u0); ACC8(u1); ACC8(u2); ACC8(u3);                              \
        qq += 4;                                                             \
    }                                                                        \
    if (qq + 2 <= ns) {                                                      \
        int b0 = r0 + qq * 2 + g;                                            \
        int j0 = ssrc[b0];                                                   \
        int j1 = ssrc[b0 + 2];                                               \
        uint4 u0 = *(const uint4*)(m_ptr + (long)j0 * 64 + f8);              \
        uint4 u1 = *(const uint4*)(m_ptr + (long)j1 * 64 + f8);              \
        ACC8(u0); ACC8(u1);                                                  \
        qq += 2;                                                             \
    }                                                                        \
    if (qq < ns) {                                                           \
        int j0 = ssrc[r0 + qq * 2 + g];                                      \
        uint4 u0 = *(const uint4*)(m_ptr + (long)j0 * 64 + f8);              \
        ACC8(u0);                                                            \
    }                                                                        \
    if ((nedge & 1) && g == 0) {                                             \
        int j0 = ssrc[r0 + ns * 2];                                          \
        uint4 u0 = *(const uint4*)(m_ptr + (long)j0 * 64 + f8);              \
        ACC8(u0);                                                            \
    }

// Fused gather_i + gemm_{i+1} (R7 structure, 8-deep gather body).
__global__ void __launch_bounds__(512) gg_kernel(
    const __half* __restrict__ m_in, const __half* __restrict__ aout_in,
    const int* __restrict__ rowp, const int* __restrict__ ssrc,
    float aggscale,
    const float* __restrict__ relW, const float* __restrict__ relb,
    const float* __restrict__ rootW,
    __half* __restrict__ m_out, __half* __restrict__ aout_out) {
    __shared__ __align__(16) __half hs[128 * 64];
    __shared__ __align__(16) __half ws[128 * 64];
    int tid = threadIdx.x;
    int i0 = blockIdx.x * 128;
    int lane = tid & 63;
    int w = tid >> 6;            // wave 0..7
    // ---- Phase W: weights ----
#pragma unroll
    for (int it = 0; it < 2; it++) {
        int t = it * 512 + tid;
        int row = t >> 3, c = t & 7;
        const float* wsrc = (row < 64) ? &relW[row * 64 + c * 8]
                                       : &rootW[(row - 64) * 64 + c * 8];
        float4 w0 = *(const float4*)wsrc;
        float4 w1 = *(const float4*)(wsrc + 4);
        uint4 pk;
        __half2* hp = (__half2*)&pk;
        hp[0] = __floats2half2_rn(w0.x, w0.y);
        hp[1] = __floats2half2_rn(w0.z, w0.w);
        hp[2] = __floats2half2_rn(w1.x, w1.y);
        hp[3] = __floats2half2_rn(w1.z, w1.w);
        *(uint4*)&ws[row * 64 + ((c ^ (row & 7)) << 3)] = pk;
    }
    // ---- Phase G: gather 128 nodes in 4 passes ----
    int n = lane >> 4;          // node quarter within wave
    int g = (lane >> 3) & 1;    // edge subgroup 0/1
    int f8 = (lane & 7) << 3;   // feature oct base
#pragma unroll
    for (int pass = 0; pass < 4; pass++) {
        int nl = pass * 32 + (w << 2);   // local node base (uniform per wave)
        int pb = __builtin_amdgcn_readfirstlane(i0 + nl);
        int x0 = pb + 0 < N_NODES ? pb + 0 : N_NODES;
        int x1 = pb + 1 < N_NODES ? pb + 1 : N_NODES;
        int x2 = pb + 2 < N_NODES ? pb + 2 : N_NODES;
        int x3 = pb + 3 < N_NODES ? pb + 3 : N_NODES;
        int x4 = pb + 4 < N_NODES ? pb + 4 : N_NODES;
        int q0 = rowp[x0], q1 = rowp[x1], q2 = rowp[x2], q3 = rowp[x3], q4 = rowp[x4];
        int node = pb + n;
        int r0 = (n == 0) ? q0 : (n == 1) ? q1 : (n == 2) ? q2 : q3;
        int r1 = (n == 0) ? q1 : (n == 1) ? q2 : (n == 2) ? q3 : q4;
        int nedge = r1 - r0;
        uint4 av = {0u, 0u, 0u, 0u};
        if (node < N_NODES) av = *(const uint4*)(aout_in + (long)node * 64 + f8);
        float a0 = 0.f, a1 = 0.f, a2 = 0.f, a3 = 0.f;
        float a4 = 0.f, a5 = 0.f, a6 = 0.f, a7 = 0.f;
#define ACC8(u)                                                         \
    {                                                                   \
        float2 f_;                                                      \
        f_ = __half22float2(*(__half2*)&(u).x); a0 += f_.x; a1 += f_.y; \
        f_ = __half22float2(*(__half2*)&(u).y); a2 += f_.x; a3 += f_.y; \
        f_ = __half22float2(*(__half2*)&(u).z); a4 += f_.x; a5 += f_.y; \
        f_ = __half22float2(*(__half2*)&(u).w); a6 += f_.x; a7 += f_.y; \
    }
        GATHER_BODY(m_in)
#undef ACC8
        a0 += __shfl_xor(a0, 8, 64); a1 += __shfl_xor(a1, 8, 64);
        a2 += __shfl_xor(a2, 8, 64); a3 += __shfl_xor(a3, 8, 64);
        a4 += __shfl_xor(a4, 8, 64); a5 += __shfl_xor(a5, 8, 64);
        a6 += __shfl_xor(a6, 8, 64); a7 += __shfl_xor(a7, 8, 64);
        a0 *= aggscale; a1 *= aggscale; a2 *= aggscale; a3 *= aggscale;
        a4 *= aggscale; a5 *= aggscale; a6 *= aggscale; a7 *= aggscale;
        const __half2* ap = (const __half2*)&av;
        float2 o0 = __half22float2(ap[0]), o1 = __half22float2(ap[1]);
        float2 o2 = __half22float2(ap[2]), o3 = __half22float2(ap[3]);
        a0 = fmaxf(fmaf(o0.x, HSCI, a0), 0.f); a1 = fmaxf(fmaf(o0.y, HSCI, a1), 0.f);
        a2 = fmaxf(fmaf(o1.x, HSCI, a2), 0.f); a3 = fmaxf(fmaf(o1.y, HSCI, a3), 0.f);
        a4 = fmaxf(fmaf(o2.x, HSCI, a4), 0.f); a5 = fmaxf(fmaf(o2.y, HSCI, a5), 0.f);
        a6 = fmaxf(fmaf(o3.x, HSCI, a6), 0.f); a7 = fmaxf(fmaf(o3.y, HSCI, a7), 0.f);
        if (g == 0) {
            int row = nl + n;          // local row 0..127
            int c = lane & 7;
            uint4 st;
            __half2* sp = (__half2*)&st;
            sp[0] = __floats2half2_rn(a0 * HSC, a1 * HSC);
            sp[1] = __floats2half2_rn(a2 * HSC, a3 * HSC);
            sp[2] = __floats2half2_rn(a4 * HSC, a5 * HSC);
            sp[3] = __floats2half2_rn(a6 * HSC, a7 * HSC);
            *(uint4*)&hs[row * 64 + ((c ^ (row & 7)) << 3)] = st;
        }
    }
    __syncthreads();
    // ---- Phase M: MFMA ----
    int wm = w >> 1, wn = w & 1;
    int r = lane & 15, q = lane >> 4;
    f32x4 acc[2][4];
#pragma unroll
    for (int mt = 0; mt < 2; mt++)
#pragma unroll
        for (int nt = 0; nt < 4; nt++) acc[mt][nt] = (f32x4){0.f, 0.f, 0.f, 0.f};
#pragma unroll
    for (int ks = 0; ks < 2; ks++) {
        f16x8 af[2], bf[4];
#pragma unroll
        for (int mt = 0; mt < 2; mt++) {
            int row = wm * 32 + mt * 16 + r;
            int cc = (ks * 4 + q) ^ (row & 7);
            af[mt] = *(const f16x8*)&hs[row * 64 + (cc << 3)];
        }
#pragma unroll
        for (int nt = 0; nt < 4; nt++) {
            int row = wn * 64 + nt * 16 + r;
            int cc = (ks * 4 + q) ^ (row & 7);
            bf[nt] = *(const f16x8*)&ws[row * 64 + (cc << 3)];
        }
#pragma unroll
        for (int mt = 0; mt < 2; mt++)
#pragma unroll
            for (int nt = 0; nt < 4; nt++)
                acc[mt][nt] = __builtin_amdgcn_mfma_f32_16x16x32_f16(af[mt], bf[nt],
                                                                     acc[mt][nt], 0, 0, 0);
    }
    if (wn == 0) {
#pragma unroll
        for (int mt = 0; mt < 2; mt++) {
            int nb = i0 + wm * 32 + mt * 16 + q * 4;
#pragma unroll
            for (int reg = 0; reg < 4; reg++) {
                int node = nb + reg;
                if (node >= N_NODES) continue;
#pragma unroll
                for (int nt = 0; nt < 4; nt++)
                    m_out[(long)node * 64 + nt * 16 + r] = __float2half(acc[mt][nt][reg]);
            }
        }
    } else {
        float rb[4];
#pragma unroll
        for (int nt = 0; nt < 4; nt++) rb[nt] = relb[nt * 16 + r] * HSC;
#pragma unroll
        for (int mt = 0; mt < 2; mt++) {
            int nb = i0 + wm * 32 + mt * 16 + q * 4;
#pragma unroll
            for (int reg = 0; reg < 4; reg++) {
                int node = nb + reg;
                if (node >= N_NODES) continue;
#pragma unroll
                for (int nt = 0; nt < 4; nt++)
                    aout_out[(long)node * 64 + nt * 16 + r] =
                        __float2half(acc[mt][nt][reg] + rb[nt]);
            }
        }
    }
}

// Final gather + post-MLP (8-deep body).
__global__ void gather_kernel(const __half* __restrict__ m, const __half* __restrict__ a,
                              const int* __restrict__ rowp, const int* __restrict__ ssrc,
                              float aggscale,
                              const float* __restrict__ postW, const float* __restrict__ postb,
                              float* __restrict__ out) {
    int lane = threadIdx.x & 63;
    int wv = (blockIdx.x * blockDim.x + threadIdx.x) >> 6;
    int pb = wv * 4;
    if (pb >= N_NODES) return;
    int n = lane >> 4;
    int g = (lane >> 3) & 1;
    int f8 = (lane & 7) << 3;
    pb = __builtin_amdgcn_readfirstlane(pb);
    int q0 = rowp[pb], q1 = rowp[pb + 1], q2 = rowp[pb + 2];
    int q3 = rowp[pb + 3], q4 = rowp[pb + 4];
    int node = pb + n;
    int r0 = (n == 0) ? q0 : (n == 1) ? q1 : (n == 2) ? q2 : q3;
    int r1 = (n == 0) ? q1 : (n == 1) ? q2 : (n == 2) ? q3 : q4;
    int nedge = r1 - r0;
    uint4 av = *(const uint4*)(a + (long)node * 64 + f8);
    float a0 = 0.f, a1 = 0.f, a2 = 0.f, a3 = 0.f, a4 = 0.f, a5 = 0.f, a6 = 0.f, a7 = 0.f;
#define ACC8(u)                                                         \
    {                                                                   \
        float2 f_;                                                      \
        f_ = __half22float2(*(__half2*)&(u).x); a0 += f_.x; a1 += f_.y; \
        f_ = __half22float2(*(__half2*)&(u).y); a2 += f_.x; a3 += f_.y; \
        f_ = __half22float2(*(__half2*)&(u).z); a4 += f_.x; a5 += f_.y; \
        f_ = __half22float2(*(__half2*)&(u).w); a6 += f_.x; a7 += f_.y; \
    }
    GATHER_BODY(m)
#undef ACC8
    a0 += __shfl_xor(a0, 8, 64); a1 += __shfl_xor(a1, 8, 64);
    a2 += __shfl_xor(a2, 8, 64); a3 += __shfl_xor(a3, 8, 64);
    a4 += __shfl_xor(a4, 8, 64); a5 += __shfl_xor(a5, 8, 64);
    a6 += __shfl_xor(a6, 8, 64); a7 += __shfl_xor(a7, 8, 64);
    a0 *= aggscale; a1 *= aggscale; a2 *= aggscale; a3 *= aggscale;
    a4 *= aggscale; a5 *= aggscale; a6 *= aggscale; a7 *= aggscale;
    const __half2* ap = (const __half2*)&av;
    float2 o0 = __half22float2(ap[0]), o1 = __half22float2(ap[1]);
    float2 o2 = __half22float2(ap[2]), o3 = __half22float2(ap[3]);
    a0 = fmaxf(fmaf(o0.x, HSCI, a0), 0.f); a1 = fmaxf(fmaf(o0.y, HSCI, a1), 0.f);
    a2 = fmaxf(fmaf(o1.x, HSCI, a2), 0.f); a3 = fmaxf(fmaf(o1.y, HSCI, a3), 0.f);
    a4 = fmaxf(fmaf(o2.x, HSCI, a4), 0.f); a5 = fmaxf(fmaf(o2.y, HSCI, a5), 0.f);
    a6 = fmaxf(fmaf(o3.x, HSCI, a6), 0.f); a7 = fmaxf(fmaf(o3.y, HSCI, a7), 0.f);
    float4 w0 = *(const float4*)(postW + f8);
    float4 w1 = *(const float4*)(postW + f8 + 4);
    float4 w2 = *(const float4*)(postW + 64 + f8);
    float4 w3 = *(const float4*)(postW + 64 + f8 + 4);
    float p0 = a0 * w0.x + a1 * w0.y + a2 * w0.z + a3 * w0.w +
               a4 * w1.x + a5 * w1.y + a6 * w1.z + a7 * w1.w;
    float p1 = a0 * w2.x + a1 * w2.y + a2 * w2.z + a3 * w2.w +
               a4 * w3.x + a5 * w3.y + a6 * w3.z + a7 * w3.w;
#pragma unroll
    for (int off = 1; off <= 4; off <<= 1) {
        p0 += __shfl_xor(p0, off, 64);
        p1 += __shfl_xor(p1, off, 64);
    }
    if ((lane & 15) == 0) {
        out[(long)node * 2 + 0] = fmaxf(p0 + postb[0], 0.f);
        out[(long)node * 2 + 1] = fmaxf(p1 + postb[1], 0.f);
    }
}

extern "C" void kernel_launch(void* const* d_in, const int* in_sizes, int n_in,
                              void* d_out, int out_size, void* d_ws, size_t ws_size,
                              hipStream_t stream) {
    const float* x = (const float*)d_in[0];
    const int* esrc = (const int*)d_in[1];
    const int* edst = esrc + N_EDGES;
    const float* preW = (const float*)d_in[2];
    const float* preb = (const float*)d_in[3];
    const float* postW = (const float*)d_in[4];
    const float* postb = (const float*)d_in[5];
    const float* relW[3] = {(const float*)d_in[6], (const float*)d_in[9], (const float*)d_in[12]};
    const float* relb[3] = {(const float*)d_in[7], (const float*)d_in[10], (const float*)d_in[13]};
    const float* rootW[3] = {(const float*)d_in[8], (const float*)d_in[11], (const float*)d_in[14]};
    float* out = (float*)d_out;

    const size_t NF = (size_t)N_NODES * HID;
    char* p = (char*)d_ws;
    __half* mA = (__half*)p; p += NF * 2;
    __half* mB = (__half*)p; p += NF * 2;
    __half* aA = (__half*)p; p += NF * 2;
    __half* aB = (__half*)p; p += NF * 2;
    p = (char*)(((size_t)p + 255) & ~(size_t)255);
    int* rowp = (int*)p; p += (size_t)(N_NODES + 1) * 4;
    p = (char*)(((size_t)p + 255) & ~(size_t)255);
    int* ssrc = (int*)p; p += (size_t)N_EDGES * 4;
    p = (char*)(((size_t)p + 255) & ~(size_t)255);
    unsigned int* tmp = (unsigned int*)p; p += (size_t)NBKT * CAP * 4;  // dedicated
    int* bcur = (int*)p; p += 512 * 4;

    const int GEMM_BLOCKS = (N_NODES + 127) / 128;      // 782
    const int GATHER_BLOCKS = N_NODES / 16;             // final gather
    const float IS1 = 64.0f;

    hipMemsetAsync(bcur, 0, 512 * 4, stream);
    // {bucket 391 blocks} ∥ {layer-0 PRE gemm 782 blocks}; m_0 -> mA, aout_0 -> aA
    fused0_kernel<<<NCHUNK + GEMM_BLOCKS, 512, 41216, stream>>>(
        esrc, edst, bcur, tmp, x, preW, preb, relW[0], relb[0], rootW[0], mA, aA);
    passb_kernel<<<NBKT, 256, 0, stream>>>(tmp, bcur, rowp, ssrc);
    // gather_0 + gemm_1: (mA, aA) -> (mB, aB)
    gg_kernel<<<GEMM_BLOCKS, 512, 0, stream>>>(mA, aA, rowp, ssrc, 1.0f,
                                               relW[1], relb[1], rootW[1], mB, aB);
    // gather_1 + gemm_2: (mB, aB) -> (mA, aA)
    gg_kernel<<<GEMM_BLOCKS, 512, 0, stream>>>(mB, aB, rowp, ssrc, IS1,
                                               relW[2], relb[2], rootW[2], mA, aA);
    // gather_2 + post: (mA, aA) -> out
    gather_kernel<<<GATHER_BLOCKS, 256, 0, stream>>>(mA, aA, rowp, ssrc, IS1,
                                                     postW, postb, out);
}

// Round 10
// 253.886 us; speedup vs baseline: 1.0061x; 1.0061x over previous
//
#include <hip/hip_runtime.h>
#include <hip/hip_fp16.h>

#define N_NODES 100000
#define N_EDGES 1600000
#define HID 64

#define BSH 8                         // bucket = dst >> 8 (256 nodes per bucket)
#define NBKT ((N_NODES + 255) / 256)  // 391
#define CAP 6144                      // fixed tmp region per bucket (mean 4093, sd 64)
#define TILE 4096                     // edges per bucket chunk (32 KB LDS)
#define NCHUNK ((N_EDGES + TILE - 1) / TILE)  // 391

#define HSC 0.015625f                 // 1/64: fp16 range scaling for h/aout (exact pow2)
#define HSCI 64.0f

typedef _Float16 f16x8 __attribute__((ext_vector_type(8)));
typedef float f32x4 __attribute__((ext_vector_type(4)));

// Fused {edge bucketing ∥ layer-0 PRE-gemm} fat kernel (R6, verbatim).
__global__ void __launch_bounds__(512) fused0_kernel(
    const int* __restrict__ src, const int* __restrict__ dst,
    int* __restrict__ bcur, unsigned int* __restrict__ tmp,
    const float* __restrict__ x, const float* __restrict__ preW,
    const float* __restrict__ preb, const float* __restrict__ relW,
    const float* __restrict__ relb, const float* __restrict__ rootW,
    __half* __restrict__ m, __half* __restrict__ aout) {
    extern __shared__ __align__(16) char smem[];
    int tid = threadIdx.x;
    if (blockIdx.x < NCHUNK) {
        unsigned long long* ed = (unsigned long long*)smem;  // 32 KB
        int* cnt = (int*)(smem + 32768);
        int* cnt2 = (int*)(smem + 34368);
        int* scnx = (int*)(smem + 35968);
        int* gbase = (int*)(smem + 37568);
        int* s = (int*)(smem + 39168);                        // 2 KB -> 41216
        int bstart = blockIdx.x * TILE;
        int tcnt = N_EDGES - bstart;
        if (tcnt > TILE) tcnt = TILE;
        if (tcnt < 0) tcnt = 0;
        for (int b = tid; b < NBKT; b += 512) { cnt[b] = 0; cnt2[b] = 0; }
        __syncthreads();
        for (int i = tid; i < tcnt; i += 512) atomicAdd(&cnt[dst[bstart + i] >> BSH], 1);
        __syncthreads();
        s[tid] = (tid < NBKT) ? cnt[tid] : 0;
        __syncthreads();
        for (int off = 1; off < 512; off <<= 1) {
            int add = (tid >= off) ? s[tid - off] : 0;
            __syncthreads();
            s[tid] += add;
            __syncthreads();
        }
        if (tid < NBKT) {
            scnx[tid] = s[tid] - cnt[tid];
            gbase[tid] = tid * CAP + atomicAdd(&bcur[tid], cnt[tid]);
        }
        __syncthreads();
        for (int i = tid; i < tcnt; i += 512) {
            int e = bstart + i;
            int d = dst[e], sc = src[e];
            int b = d >> BSH;
            int pos = scnx[b] + atomicAdd(&cnt2[b], 1);
            ed[pos] = ((unsigned long long)(unsigned)d << 32) | (unsigned)sc;
        }
        __syncthreads();
        for (int i = tid; i < tcnt; i += 512) {
            unsigned long long v = ed[i];
            int d = (int)(v >> 32);
            unsigned sc = (unsigned)v;
            int b = d >> BSH;
            int idx = gbase[b] + (i - scnx[b]);
            if (idx < (b + 1) * CAP)  // statistically unreachable guard
                tmp[idx] = ((unsigned)(d & 255) << 17) | sc;
        }
    } else {
        __half* hs = (__half*)smem;              // 16 KB
        __half* ws = (__half*)(smem + 16384);    // 16 KB
        float* xs = (float*)(smem + 32768);      // 384 f
        float* pw = (float*)(smem + 34304);      // 192 f
        float* pbs = (float*)(smem + 35072);     // 64 f -> 35328
        int g = blockIdx.x - NCHUNK;
        int i0 = g * 128;
#pragma unroll
        for (int it = 0; it < 2; it++) {
            int t = it * 512 + tid;
            int row = t >> 3, c = t & 7;
            const float* wsrc = (row < 64) ? &relW[row * 64 + c * 8]
                                           : &rootW[(row - 64) * 64 + c * 8];
            float4 w0 = *(const float4*)wsrc;
            float4 w1 = *(const float4*)(wsrc + 4);
            uint4 pk;
            __half2* hp = (__half2*)&pk;
            hp[0] = __floats2half2_rn(w0.x, w0.y);
            hp[1] = __floats2half2_rn(w0.z, w0.w);
            hp[2] = __floats2half2_rn(w1.x, w1.y);
            hp[3] = __floats2half2_rn(w1.z, w1.w);
            *(uint4*)&ws[row * 64 + ((c ^ (row & 7)) << 3)] = pk;
        }
        if (tid < 192) pw[tid] = preW[tid];
        if (tid < 64) pbs[tid] = preb[tid];
        if (tid < 384) {  // 512 threads fully cover xs[0..383]
            int gi = i0 * 3 + tid;
            xs[tid] = (gi < N_NODES * 3) ? x[gi] : 0.f;
        }
        __syncthreads();
#pragma unroll
        for (int it = 0; it < 2; it++) {
            int t = it * 512 + tid;
            int row = t >> 3, c = t & 7;
            float v[8];
#pragma unroll
            for (int u = 0; u < 8; u++) {
                int col = c * 8 + u;
                float sv = pbs[col];
                sv = fmaf(xs[row * 3 + 0], pw[col * 3 + 0], sv);
                sv = fmaf(xs[row * 3 + 1], pw[col * 3 + 1], sv);
                sv = fmaf(xs[row * 3 + 2], pw[col * 3 + 2], sv);
                v[u] = fmaxf(sv, 0.f);
            }
            uint4 pk;
            __half2* hp = (__half2*)&pk;
            hp[0] = __floats2half2_rn(v[0], v[1]);
            hp[1] = __floats2half2_rn(v[2], v[3]);
            hp[2] = __floats2half2_rn(v[4], v[5]);
            hp[3] = __floats2half2_rn(v[6], v[7]);
            *(uint4*)&hs[row * 64 + ((c ^ (row & 7)) << 3)] = pk;
        }
        __syncthreads();
        int lane = tid & 63;
        int w = tid >> 6;             // wave 0..7
        int wm = w >> 1, wn = w & 1;  // 4x2 wave grid
        int r = lane & 15, q = lane >> 4;
        f32x4 acc[2][4];
#pragma unroll
        for (int mt = 0; mt < 2; mt++)
#pragma unroll
            for (int nt = 0; nt < 4; nt++) acc[mt][nt] = (f32x4){0.f, 0.f, 0.f, 0.f};
#pragma unroll
        for (int ks = 0; ks < 2; ks++) {
            f16x8 af[2], bf[4];
#pragma unroll
            for (int mt = 0; mt < 2; mt++) {
                int row = wm * 32 + mt * 16 + r;
                int cc = (ks * 4 + q) ^ (row & 7);
                af[mt] = *(const f16x8*)&hs[row * 64 + (cc << 3)];
            }
#pragma unroll
            for (int nt = 0; nt < 4; nt++) {
                int row = wn * 64 + nt * 16 + r;
                int cc = (ks * 4 + q) ^ (row & 7);
                bf[nt] = *(const f16x8*)&ws[row * 64 + (cc << 3)];
            }
#pragma unroll
            for (int mt = 0; mt < 2; mt++)
#pragma unroll
                for (int nt = 0; nt < 4; nt++)
                    acc[mt][nt] = __builtin_amdgcn_mfma_f32_16x16x32_f16(af[mt], bf[nt],
                                                                         acc[mt][nt], 0, 0, 0);
        }
        if (wn == 0) {
#pragma unroll
            for (int mt = 0; mt < 2; mt++) {
                int nb = i0 + wm * 32 + mt * 16 + q * 4;
#pragma unroll
                for (int reg = 0; reg < 4; reg++) {
                    int node = nb + reg;
                    if (node >= N_NODES) continue;
#pragma unroll
                    for (int nt = 0; nt < 4; nt++)
                        m[(long)node * 64 + nt * 16 + r] = __float2half(acc[mt][nt][reg]);
                }
            }
        } else {
            float rb[4];
#pragma unroll
            for (int nt = 0; nt < 4; nt++) rb[nt] = relb[nt * 16 + r] * HSC;
#pragma unroll
            for (int mt = 0; mt < 2; mt++) {
                int nb = i0 + wm * 32 + mt * 16 + q * 4;
#pragma unroll
                for (int reg = 0; reg < 4; reg++) {
                    int node = nb + reg;
                    if (node >= N_NODES) continue;
#pragma unroll
                    for (int nt = 0; nt < 4; nt++)
                        aout[(long)node * 64 + nt * 16 + r] =
                            __float2half(fmaf(acc[mt][nt][reg], HSC, rb[nt]));
                }
            }
        }
    }
}

// Pass B: per bucket CSR finalize (R1 verbatim).
__global__ void __launch_bounds__(256) passb_kernel(const unsigned int* __restrict__ tmp,
                                                    const int* __restrict__ bcur,
                                                    int* __restrict__ rowp,
                                                    int* __restrict__ ssrc) {
    __shared__ int red[256];
    __shared__ int cnt[256], s[256], cur[256];
    int tid = threadIdx.x;
    int b = blockIdx.x;
    int acc = 0;
    for (int i = tid; i < b; i += 256) {
        int c = bcur[i];
        if (c > CAP) c = CAP;
        acc += c;
    }
    red[tid] = acc;
    __syncthreads();
    for (int off = 128; off >= 1; off >>= 1) {
        if (tid < off) red[tid] += red[tid + off];
        __syncthreads();
    }
    int lo = red[0];
    int ne = bcur[b];
    if (ne > CAP) ne = CAP;
    if (b == NBKT - 1 && tid == 0) rowp[N_NODES] = lo + ne;
    int lo_t = b * CAP;
    cnt[tid] = 0;
    __syncthreads();
    for (int i = tid; i < ne; i += 256) atomicAdd(&cnt[tmp[lo_t + i] >> 17], 1);
    __syncthreads();
    int v = cnt[tid];
    s[tid] = v;
    __syncthreads();
    for (int off = 1; off < 256; off <<= 1) {
        int a = (tid >= off) ? s[tid - off] : 0;
        __syncthreads();
        s[tid] += a;
        __syncthreads();
    }
    int excl = lo + s[tid] - v;
    int node = (b << BSH) + tid;
    if (node < N_NODES) rowp[node] = excl;
    cur[tid] = excl;
    __syncthreads();
    for (int i = tid; i < ne; i += 256) {
        unsigned u = tmp[lo_t + i];
        int pos = atomicAdd(&cur[u >> 17], 1);
        ssrc[pos] = (int)(u & 0x1FFFF);
    }
}

// 8-deep gather body (R8, measured: gg 54.4 -> 49.2 µs). Used in gg only;
// the final gather keeps the R6 4-deep shape (R8 post-mortem: 8-deep there
// coincided with a ~10 µs total regression — revert, attribute).
#define GATHER_BODY(m_ptr)                                                   \
    int ns = nedge >> 1;                                                     \
    int qq = 0;                                                              \
    for (; qq + 8 <= ns; qq += 8) {                                          \
        int b0 = r0 + qq * 2 + g;                                            \
        int j0 = ssrc[b0];                                                   \
        int j1 = ssrc[b0 + 2];                                               \
        int j2 = ssrc[b0 + 4];                                               \
        int j3 = ssrc[b0 + 6];                                               \
        int j4 = ssrc[b0 + 8];                                               \
        int j5 = ssrc[b0 + 10];                                              \
        int j6 = ssrc[b0 + 12];                                              \
        int j7 = ssrc[b0 + 14];                                              \
        uint4 u0 = *(const uint4*)(m_ptr + (long)j0 * 64 + f8);              \
        uint4 u1 = *(const uint4*)(m_ptr + (long)j1 * 64 + f8);              \
        uint4 u2 = *(const uint4*)(m_ptr + (long)j2 * 64 + f8);              \
        uint4 u3 = *(const uint4*)(m_ptr + (long)j3 * 64 + f8);              \
        uint4 u4 = *(const uint4*)(m_ptr + (long)j4 * 64 + f8);              \
        uint4 u5 = *(const uint4*)(m_ptr + (long)j5 * 64 + f8);              \
        uint4 u6 = *(const uint4*)(m_ptr + (long)j6 * 64 + f8);              \
        uint4 u7 = *(const uint4*)(m_ptr + (long)j7 * 64 + f8);              \
        ACC8(u0); ACC8(u1); ACC8(u2); ACC8(u3);                              \
        ACC8(u4); ACC8(u5); ACC8(u6); ACC8(u7);                              \
    }                                                                        \
    if (qq + 4 <= ns) {                                                      \
        int b0 = r0 + qq * 2 + g;                                            \
        int j0 = ssrc[b0];                                                   \
        int j1 = ssrc[b0 + 2];                                               \
        int j2 = ssrc[b0 + 4];                                               \
        int j3 = ssrc[b0 + 6];                                               \
        uint4 u0 = *(const uint4*)(m_ptr + (long)j0 * 64 + f8);              \
        uint4 u1 = *(const uint4*)(m_ptr + (long)j1 * 64 + f8);              \
        uint4 u2 = *(const uint4*)(m_ptr + (long)j2 * 64 + f8);              \
        uint4 u3 = *(const uint4*)(m_ptr + (long)j3 * 64 + f8);              \
        ACC8(u0); ACC8(u1); ACC8(u2); ACC8(u3);                              \
        qq += 4;                                                             \
    }                                                                        \
    if (qq + 2 <= ns) {                                                      \
        int b0 = r0 + qq * 2 + g;                                            \
        int j0 = ssrc[b0];                                                   \
        int j1 = ssrc[b0 + 2];                                               \
        uint4 u0 = *(const uint4*)(m_ptr + (long)j0 * 64 + f8);              \
        uint4 u1 = *(const uint4*)(m_ptr + (long)j1 * 64 + f8);              \
        ACC8(u0); ACC8(u1);                                                  \
        qq += 2;                                                             \
    }                                                                        \
    if (qq < ns) {                                                           \
        int j0 = ssrc[r0 + qq * 2 + g];                                      \
        uint4 u0 = *(const uint4*)(m_ptr + (long)j0 * 64 + f8);              \
        ACC8(u0);                                                            \
    }                                                                        \
    if ((nedge & 1) && g == 0) {                                             \
        int j0 = ssrc[r0 + ns * 2];                                          \
        uint4 u0 = *(const uint4*)(m_ptr + (long)j0 * 64 + f8);              \
        ACC8(u0);                                                            \
    }

// Fused gather_i + gemm_{i+1} (R8 structure + 8-deep gather body; measured
// 49.2 µs/dispatch).
__global__ void __launch_bounds__(512) gg_kernel(
    const __half* __restrict__ m_in, const __half* __restrict__ aout_in,
    const int* __restrict__ rowp, const int* __restrict__ ssrc,
    float aggscale,
    const float* __restrict__ relW, const float* __restrict__ relb,
    const float* __restrict__ rootW,
    __half* __restrict__ m_out, __half* __restrict__ aout_out) {
    __shared__ __align__(16) __half hs[128 * 64];
    __shared__ __align__(16) __half ws[128 * 64];
    int tid = threadIdx.x;
    int i0 = blockIdx.x * 128;
    int lane = tid & 63;
    int w = tid >> 6;            // wave 0..7
    // ---- Phase W: weights ----
#pragma unroll
    for (int it = 0; it < 2; it++) {
        int t = it * 512 + tid;
        int row = t >> 3, c = t & 7;
        const float* wsrc = (row < 64) ? &relW[row * 64 + c * 8]
                                       : &rootW[(row - 64) * 64 + c * 8];
        float4 w0 = *(const float4*)wsrc;
        float4 w1 = *(const float4*)(wsrc + 4);
        uint4 pk;
        __half2* hp = (__half2*)&pk;
        hp[0] = __floats2half2_rn(w0.x, w0.y);
        hp[1] = __floats2half2_rn(w0.z, w0.w);
        hp[2] = __floats2half2_rn(w1.x, w1.y);
        hp[3] = __floats2half2_rn(w1.z, w1.w);
        *(uint4*)&ws[row * 64 + ((c ^ (row & 7)) << 3)] = pk;
    }
    // ---- Phase G: gather 128 nodes in 4 passes ----
    int n = lane >> 4;          // node quarter within wave
    int g = (lane >> 3) & 1;    // edge subgroup 0/1
    int f8 = (lane & 7) << 3;   // feature oct base
#pragma unroll
    for (int pass = 0; pass < 4; pass++) {
        int nl = pass * 32 + (w << 2);   // local node base (uniform per wave)
        int pb = __builtin_amdgcn_readfirstlane(i0 + nl);
        int x0 = pb + 0 < N_NODES ? pb + 0 : N_NODES;
        int x1 = pb + 1 < N_NODES ? pb + 1 : N_NODES;
        int x2 = pb + 2 < N_NODES ? pb + 2 : N_NODES;
        int x3 = pb + 3 < N_NODES ? pb + 3 : N_NODES;
        int x4 = pb + 4 < N_NODES ? pb + 4 : N_NODES;
        int q0 = rowp[x0], q1 = rowp[x1], q2 = rowp[x2], q3 = rowp[x3], q4 = rowp[x4];
        int node = pb + n;
        int r0 = (n == 0) ? q0 : (n == 1) ? q1 : (n == 2) ? q2 : q3;
        int r1 = (n == 0) ? q1 : (n == 1) ? q2 : (n == 2) ? q3 : q4;
        int nedge = r1 - r0;
        uint4 av = {0u, 0u, 0u, 0u};
        if (node < N_NODES) av = *(const uint4*)(aout_in + (long)node * 64 + f8);
        float a0 = 0.f, a1 = 0.f, a2 = 0.f, a3 = 0.f;
        float a4 = 0.f, a5 = 0.f, a6 = 0.f, a7 = 0.f;
#define ACC8(u)                                                         \
    {                                                                   \
        float2 f_;                                                      \
        f_ = __half22float2(*(__half2*)&(u).x); a0 += f_.x; a1 += f_.y; \
        f_ = __half22float2(*(__half2*)&(u).y); a2 += f_.x; a3 += f_.y; \
        f_ = __half22float2(*(__half2*)&(u).z); a4 += f_.x; a5 += f_.y; \
        f_ = __half22float2(*(__half2*)&(u).w); a6 += f_.x; a7 += f_.y; \
    }
        GATHER_BODY(m_in)
#undef ACC8
        a0 += __shfl_xor(a0, 8, 64); a1 += __shfl_xor(a1, 8, 64);
        a2 += __shfl_xor(a2, 8, 64); a3 += __shfl_xor(a3, 8, 64);
        a4 += __shfl_xor(a4, 8, 64); a5 += __shfl_xor(a5, 8, 64);
        a6 += __shfl_xor(a6, 8, 64); a7 += __shfl_xor(a7, 8, 64);
        a0 *= aggscale; a1 *= aggscale; a2 *= aggscale; a3 *= aggscale;
        a4 *= aggscale; a5 *= aggscale; a6 *= aggscale; a7 *= aggscale;
        const __half2* ap = (const __half2*)&av;
        float2 o0 = __half22float2(ap[0]), o1 = __half22float2(ap[1]);
        float2 o2 = __half22float2(ap[2]), o3 = __half22float2(ap[3]);
        a0 = fmaxf(fmaf(o0.x, HSCI, a0), 0.f); a1 = fmaxf(fmaf(o0.y, HSCI, a1), 0.f);
        a2 = fmaxf(fmaf(o1.x, HSCI, a2), 0.f); a3 = fmaxf(fmaf(o1.y, HSCI, a3), 0.f);
        a4 = fmaxf(fmaf(o2.x, HSCI, a4), 0.f); a5 = fmaxf(fmaf(o2.y, HSCI, a5), 0.f);
        a6 = fmaxf(fmaf(o3.x, HSCI, a6), 0.f); a7 = fmaxf(fmaf(o3.y, HSCI, a7), 0.f);
        if (g == 0) {
            int row = nl + n;          // local row 0..127
            int c = lane & 7;
            uint4 st;
            __half2* sp = (__half2*)&st;
            sp[0] = __floats2half2_rn(a0 * HSC, a1 * HSC);
            sp[1] = __floats2half2_rn(a2 * HSC, a3 * HSC);
            sp[2] = __floats2half2_rn(a4 * HSC, a5 * HSC);
            sp[3] = __floats2half2_rn(a6 * HSC, a7 * HSC);
            *(uint4*)&hs[row * 64 + ((c ^ (row & 7)) << 3)] = st;
        }
    }
    __syncthreads();
    // ---- Phase M: MFMA ----
    int wm = w >> 1, wn = w & 1;
    int r = lane & 15, q = lane >> 4;
    f32x4 acc[2][4];
#pragma unroll
    for (int mt = 0; mt < 2; mt++)
#pragma unroll
        for (int nt = 0; nt < 4; nt++) acc[mt][nt] = (f32x4){0.f, 0.f, 0.f, 0.f};
#pragma unroll
    for (int ks = 0; ks < 2; ks++) {
        f16x8 af[2], bf[4];
#pragma unroll
        for (int mt = 0; mt < 2; mt++) {
            int row = wm * 32 + mt * 16 + r;
            int cc = (ks * 4 + q) ^ (row & 7);
            af[mt] = *(const f16x8*)&hs[row * 64 + (cc << 3)];
        }
#pragma unroll
        for (int nt = 0; nt < 4; nt++) {
            int row = wn * 64 + nt * 16 + r;
            int cc = (ks * 4 + q) ^ (row & 7);
            bf[nt] = *(const f16x8*)&ws[row * 64 + (cc << 3)];
        }
#pragma unroll
        for (int mt = 0; mt < 2; mt++)
#pragma unroll
            for (int nt = 0; nt < 4; nt++)
                acc[mt][nt] = __builtin_amdgcn_mfma_f32_16x16x32_f16(af[mt], bf[nt],
                                                                     acc[mt][nt], 0, 0, 0);
    }
    if (wn == 0) {
#pragma unroll
        for (int mt = 0; mt < 2; mt++) {
            int nb = i0 + wm * 32 + mt * 16 + q * 4;
#pragma unroll
            for (int reg = 0; reg < 4; reg++) {
                int node = nb + reg;
                if (node >= N_NODES) continue;
#pragma unroll
                for (int nt = 0; nt < 4; nt++)
                    m_out[(long)node * 64 + nt * 16 + r] = __float2half(acc[mt][nt][reg]);
            }
        }
    } else {
        float rb[4];
#pragma unroll
        for (int nt = 0; nt < 4; nt++) rb[nt] = relb[nt * 16 + r] * HSC;
#pragma unroll
        for (int mt = 0; mt < 2; mt++) {
            int nb = i0 + wm * 32 + mt * 16 + q * 4;
#pragma unroll
            for (int reg = 0; reg < 4; reg++) {
                int node = nb + reg;
                if (node >= N_NODES) continue;
#pragma unroll
                for (int nt = 0; nt < 4; nt++)
                    aout_out[(long)node * 64 + nt * 16 + r] =
                        __float2half(acc[mt][nt][reg] + rb[nt]);
            }
        }
    }
}

// Final gather + post-MLP: R6-verbatim 4-deep body (reverted from 8-deep —
// R8 attribution: the 8-deep final gather coincided with a ~10 µs total).
__global__ void gather_kernel(const __half* __restrict__ m, const __half* __restrict__ a,
                              const int* __restrict__ rowp, const int* __restrict__ ssrc,
                              float aggscale,
                              const float* __restrict__ postW, const float* __restrict__ postb,
                              float* __restrict__ out) {
    int lane = threadIdx.x & 63;
    int wv = (blockIdx.x * blockDim.x + threadIdx.x) >> 6;
    int pb = wv * 4;
    if (pb >= N_NODES) return;
    int n = lane >> 4;
    int g = (lane >> 3) & 1;
    int f8 = (lane & 7) << 3;
    pb = __builtin_amdgcn_readfirstlane(pb);
    int q0 = rowp[pb], q1 = rowp[pb + 1], q2 = rowp[pb + 2];
    int q3 = rowp[pb + 3], q4 = rowp[pb + 4];
    int node = pb + n;
    int r0 = (n == 0) ? q0 : (n == 1) ? q1 : (n == 2) ? q2 : q3;
    int r1 = (n == 0) ? q1 : (n == 1) ? q2 : (n == 2) ? q3 : q4;
    int nedge = r1 - r0;
    uint4 av = *(const uint4*)(a + (long)node * 64 + f8);
    float a0 = 0.f, a1 = 0.f, a2 = 0.f, a3 = 0.f, a4 = 0.f, a5 = 0.f, a6 = 0.f, a7 = 0.f;
#define ACC8(u)                                                         \
    {                                                                   \
        float2 f_;                                                      \
        f_ = __half22float2(*(__half2*)&(u).x); a0 += f_.x; a1 += f_.y; \
        f_ = __half22float2(*(__half2*)&(u).y); a2 += f_.x; a3 += f_.y; \
        f_ = __half22float2(*(__half2*)&(u).z); a4 += f_.x; a5 += f_.y; \
        f_ = __half22float2(*(__half2*)&(u).w); a6 += f_.x; a7 += f_.y; \
    }
    int ns = nedge >> 1;
    int q = 0;
    for (; q + 4 <= ns; q += 4) {
        int b0 = r0 + q * 2 + g;
        int i0 = ssrc[b0];
        int i1 = ssrc[b0 + 2];
        int i2 = ssrc[b0 + 4];
        int i3 = ssrc[b0 + 6];
        uint4 u0 = *(const uint4*)(m + (long)i0 * 64 + f8);
        uint4 u1 = *(const uint4*)(m + (long)i1 * 64 + f8);
        uint4 u2 = *(const uint4*)(m + (long)i2 * 64 + f8);
        uint4 u3 = *(const uint4*)(m + (long)i3 * 64 + f8);
        ACC8(u0); ACC8(u1); ACC8(u2); ACC8(u3);
    }
    if (q + 2 <= ns) {
        int b0 = r0 + q * 2 + g;
        int i0 = ssrc[b0];
        int i1 = ssrc[b0 + 2];
        uint4 u0 = *(const uint4*)(m + (long)i0 * 64 + f8);
        uint4 u1 = *(const uint4*)(m + (long)i1 * 64 + f8);
        ACC8(u0); ACC8(u1);
        q += 2;
    }
    if (q < ns) {
        int i0 = ssrc[r0 + q * 2 + g];
        uint4 u0 = *(const uint4*)(m + (long)i0 * 64 + f8);
        ACC8(u0);
    }
    if ((nedge & 1) && g == 0) {
        int i0 = ssrc[r0 + ns * 2];
        uint4 u0 = *(const uint4*)(m + (long)i0 * 64 + f8);
        ACC8(u0);
    }
#undef ACC8
    a0 += __shfl_xor(a0, 8, 64); a1 += __shfl_xor(a1, 8, 64);
    a2 += __shfl_xor(a2, 8, 64); a3 += __shfl_xor(a3, 8, 64);
    a4 += __shfl_xor(a4, 8, 64); a5 += __shfl_xor(a5, 8, 64);
    a6 += __shfl_xor(a6, 8, 64); a7 += __shfl_xor(a7, 8, 64);
    a0 *= aggscale; a1 *= aggscale; a2 *= aggscale; a3 *= aggscale;
    a4 *= aggscale; a5 *= aggscale; a6 *= aggscale; a7 *= aggscale;
    const __half2* ap = (const __half2*)&av;
    float2 o0 = __half22float2(ap[0]), o1 = __half22float2(ap[1]);
    float2 o2 = __half22float2(ap[2]), o3 = __half22float2(ap[3]);
    a0 = fmaxf(fmaf(o0.x, HSCI, a0), 0.f); a1 = fmaxf(fmaf(o0.y, HSCI, a1), 0.f);
    a2 = fmaxf(fmaf(o1.x, HSCI, a2), 0.f); a3 = fmaxf(fmaf(o1.y, HSCI, a3), 0.f);
    a4 = fmaxf(fmaf(o2.x, HSCI, a4), 0.f); a5 = fmaxf(fmaf(o2.y, HSCI, a5), 0.f);
    a6 = fmaxf(fmaf(o3.x, HSCI, a6), 0.f); a7 = fmaxf(fmaf(o3.y, HSCI, a7), 0.f);
    float4 w0 = *(const float4*)(postW + f8);
    float4 w1 = *(const float4*)(postW + f8 + 4);
    float4 w2 = *(const float4*)(postW + 64 + f8);
    float4 w3 = *(const float4*)(postW + 64 + f8 + 4);
    float p0 = a0 * w0.x + a1 * w0.y + a2 * w0.z + a3 * w0.w +
               a4 * w1.x + a5 * w1.y + a6 * w1.z + a7 * w1.w;
    float p1 = a0 * w2.x + a1 * w2.y + a2 * w2.z + a3 * w2.w +
               a4 * w3.x + a5 * w3.y + a6 * w3.z + a7 * w3.w;
#pragma unroll
    for (int off = 1; off <= 4; off <<= 1) {
        p0 += __shfl_xor(p0, off, 64);
        p1 += __shfl_xor(p1, off, 64);
    }
    if ((lane & 15) == 0) {
        out[(long)node * 2 + 0] = fmaxf(p0 + postb[0], 0.f);
        out[(long)node * 2 + 1] = fmaxf(p1 + postb[1], 0.f);
    }
}

extern "C" void kernel_launch(void* const* d_in, const int* in_sizes, int n_in,
                              void* d_out, int out_size, void* d_ws, size_t ws_size,
                              hipStream_t stream) {
    const float* x = (const float*)d_in[0];
    const int* esrc = (const int*)d_in[1];
    const int* edst = esrc + N_EDGES;
    const float* preW = (const float*)d_in[2];
    const float* preb = (const float*)d_in[3];
    const float* postW = (const float*)d_in[4];
    const float* postb = (const float*)d_in[5];
    const float* relW[3] = {(const float*)d_in[6], (const float*)d_in[9], (const float*)d_in[12]};
    const float* relb[3] = {(const float*)d_in[7], (const float*)d_in[10], (const float*)d_in[13]};
    const float* rootW[3] = {(const float*)d_in[8], (const float*)d_in[11], (const float*)d_in[14]};
    float* out = (float*)d_out;

    const size_t NF = (size_t)N_NODES * HID;
    char* p = (char*)d_ws;
    __half* mA = (__half*)p; p += NF * 2;
    __half* mB = (__half*)p; p += NF * 2;
    __half* aA = (__half*)p; p += NF * 2;
    __half* aB = (__half*)p; p += NF * 2;
    p = (char*)(((size_t)p + 255) & ~(size_t)255);
    int* rowp = (int*)p; p += (size_t)(N_NODES + 1) * 4;
    p = (char*)(((size_t)p + 255) & ~(size_t)255);
    int* ssrc = (int*)p; p += (size_t)N_EDGES * 4;
    p = (char*)(((size_t)p + 255) & ~(size_t)255);
    unsigned int* tmp = (unsigned int*)p; p += (size_t)NBKT * CAP * 4;  // dedicated
    int* bcur = (int*)p; p += 512 * 4;

    const int GEMM_BLOCKS = (N_NODES + 127) / 128;      // 782
    const int GATHER_BLOCKS = N_NODES / 16;             // final gather
    const float IS1 = 64.0f;

    hipMemsetAsync(bcur, 0, 512 * 4, stream);
    // {bucket 391 blocks} ∥ {layer-0 PRE gemm 782 blocks}; m_0 -> mA, aout_0 -> aA
    fused0_kernel<<<NCHUNK + GEMM_BLOCKS, 512, 41216, stream>>>(
        esrc, edst, bcur, tmp, x, preW, preb, relW[0], relb[0], rootW[0], mA, aA);
    passb_kernel<<<NBKT, 256, 0, stream>>>(tmp, bcur, rowp, ssrc);
    // gather_0 + gemm_1: (mA, aA) -> (mB, aB)
    gg_kernel<<<GEMM_BLOCKS, 512, 0, stream>>>(mA, aA, rowp, ssrc, 1.0f,
                                               relW[1], relb[1], rootW[1], mB, aB);
    // gather_1 + gemm_2: (mB, aB) -> (mA, aA)
    gg_kernel<<<GEMM_BLOCKS, 512, 0, stream>>>(mB, aB, rowp, ssrc, IS1,
                                               relW[2], relb[2], rootW[2], mA, aA);
    // gather_2 + post: (mA, aA) -> out
    gather_kernel<<<GATHER_BLOCKS, 256, 0, stream>>>(mA, aA, rowp, ssrc, IS1,
                                                     postW, postb, out);
}